// Round 4
// baseline (233.398 us; speedup 1.0000x reference)
//
#include <hip/hip_runtime.h>
#include <math.h>

typedef __attribute__((ext_vector_type(8))) short short8;
typedef __attribute__((ext_vector_type(4))) short short4v;
typedef __attribute__((ext_vector_type(4))) float floatx4;
typedef __attribute__((ext_vector_type(16))) float floatx16;

__device__ __forceinline__ unsigned short f2bf(float f) {
  union { float f; unsigned int u; } v; v.f = f;
  unsigned int r = v.u + 0x7fffu + ((v.u >> 16) & 1u);
  return (unsigned short)(r >> 16);
}

__device__ __forceinline__ unsigned int pack2(unsigned short a, unsigned short b) {
  return (unsigned int)a | ((unsigned int)b << 16);
}

__device__ __forceinline__ unsigned int rbits(float f) {
  union { float f; unsigned int u; } v; v.f = f;
  return v.u + 0x8000u;  // round-half-up to bf16 when >>16
}

__device__ __forceinline__ float fast_exp2(float x) {
#if __has_builtin(__builtin_amdgcn_exp2f)
  return __builtin_amdgcn_exp2f(x);
#else
  return exp2f(x);
#endif
}

// async global->LDS, 16B per lane. LDS dest is wave-uniform base + lane*16.
__device__ __forceinline__ void async16(const unsigned short* gp, unsigned short* lp) {
  __builtin_amdgcn_global_load_lds(
      (__attribute__((address_space(1))) void*)(gp),
      (__attribute__((address_space(3))) void*)(lp), 16, 0, 0);
}

// ---------------------------------------------------------------- GroupNorm
__global__ void gn_stats(const float* __restrict__ x, float* __restrict__ stats) {
  int bg = blockIdx.x;
  const float4* p = (const float4*)(x + (size_t)bg * 65536);
  float s = 0.f, ss = 0.f;
  for (int i = threadIdx.x; i < 16384; i += 256) {
    float4 v = p[i];
    s  += v.x + v.y + v.z + v.w;
    ss += v.x*v.x + v.y*v.y + v.z*v.z + v.w*v.w;
  }
  #pragma unroll
  for (int off = 32; off >= 1; off >>= 1) {
    s  += __shfl_xor(s,  off, 64);
    ss += __shfl_xor(ss, off, 64);
  }
  __shared__ float red[2][4];
  int wv = threadIdx.x >> 6;
  if ((threadIdx.x & 63) == 0) { red[0][wv] = s; red[1][wv] = ss; }
  __syncthreads();
  if (threadIdx.x == 0) {
    s  = red[0][0] + red[0][1] + red[0][2] + red[0][3];
    ss = red[1][0] + red[1][1] + red[1][2] + red[1][3];
    float mean = s * (1.f/65536.f);
    float var  = ss * (1.f/65536.f) - mean*mean;
    stats[2*bg]   = mean;
    stats[2*bg+1] = rsqrtf(var + 1e-5f);
  }
}

// normalize + cast bf16 + transpose to token-major h_t[B][HW][C]
__global__ void gn_apply_t(const float* __restrict__ x, const float* __restrict__ stats,
                           const float* __restrict__ gw, const float* __restrict__ gb,
                           unsigned short* __restrict__ h_t) {
  __shared__ __align__(16) unsigned short tile[64][72];
  const int b = blockIdx.z, c0 = blockIdx.y * 64, hw0 = blockIdx.x * 64;
  const int t = threadIdx.x;
  {
    const int cl = t >> 2;
    const int hs = (t & 3) * 16;
    const int c  = c0 + cl;
    const int g  = c >> 4;
    const float mean = stats[2*(b*32 + g)];
    const float rstd = stats[2*(b*32 + g) + 1];
    const float w  = gw[c] * rstd;
    const float bb = gb[c] - mean * w;
    const float4* src = (const float4*)(x + ((size_t)(b*512 + c))*4096 + hw0 + hs);
    #pragma unroll
    for (int i = 0; i < 4; i++) {
      float4 vv = src[i];
      unsigned short* d = &tile[cl][hs + i*4];
      d[0] = f2bf(vv.x*w + bb); d[1] = f2bf(vv.y*w + bb);
      d[2] = f2bf(vv.z*w + bb); d[3] = f2bf(vv.w*w + bb);
    }
  }
  __syncthreads();
  {
    const int hwl = t >> 2;
    const int cs  = (t & 3) * 16;
    uint4 w0, w1;
    w0.x = pack2(tile[cs+ 0][hwl], tile[cs+ 1][hwl]);
    w0.y = pack2(tile[cs+ 2][hwl], tile[cs+ 3][hwl]);
    w0.z = pack2(tile[cs+ 4][hwl], tile[cs+ 5][hwl]);
    w0.w = pack2(tile[cs+ 6][hwl], tile[cs+ 7][hwl]);
    w1.x = pack2(tile[cs+ 8][hwl], tile[cs+ 9][hwl]);
    w1.y = pack2(tile[cs+10][hwl], tile[cs+11][hwl]);
    w1.z = pack2(tile[cs+12][hwl], tile[cs+13][hwl]);
    w1.w = pack2(tile[cs+14][hwl], tile[cs+15][hwl]);
    unsigned short* dst = h_t + ((size_t)(b*4096 + hw0 + hwl))*512 + c0 + cs;
    *(uint4*)dst       = w0;
    *(uint4*)(dst + 8) = w1;
  }
}

// fp32 -> bf16 cast, two arrays in one launch
__global__ void castw2(const float* __restrict__ sa, unsigned short* __restrict__ da, int n4a,
                       const float* __restrict__ sb, unsigned short* __restrict__ db) {
  int i = blockIdx.x * 256 + threadIdx.x;
  const float* s; unsigned short* d;
  if (i < n4a) { s = sa; d = da; }
  else { i -= n4a; s = sb; d = db; }
  float4 vv = ((const float4*)s)[i];
  uint2 o;
  o.x = pack2(f2bf(vv.x), f2bf(vv.y));
  o.y = pack2(f2bf(vv.z), f2bf(vv.w));
  ((uint2*)d)[i] = o;
}

// ---------------------------------------------------------------- GEMM (bt)
// OUT[o][n] = sum_k A[o][k] * Bt[n][k]
// MODE 0: qkv epilogue -> q_t/k_t/v scatter; q pre-scaled by 0.125*log2(e).
//         v-region fragments run with SWAPPED mfma operands so D=[token][o],
//         giving 4 consecutive tokens/lane -> coalesced b64 stores into v_[d][tok].
// MODE 1: proj epilogue -> out = x + bias + acc  (fp32)
template <int MODE>
__global__ __launch_bounds__(256, 2)
void gemm_bt(const unsigned short* __restrict__ A,
             const unsigned short* __restrict__ Bt,
             unsigned short* __restrict__ q_t,
             unsigned short* __restrict__ k_t,
             unsigned short* __restrict__ v_,
             float* __restrict__ outp,
             const float* __restrict__ xres,
             const float* __restrict__ pbias) {
  __shared__ __align__(16) unsigned short As[128*32];
  __shared__ __align__(16) unsigned short Bs[128*32];
  const int b   = blockIdx.z;
  const int n0  = blockIdx.x * 128;
  const int o0  = blockIdx.y * 128;
  const int tid = threadIdx.x;
  const int wave = tid >> 6, lane = tid & 63;
  const int wr = wave >> 1, wc = wave & 1;
  const int fm = lane & 15, fq = lane >> 4;
  const int srow = lane >> 2, scol = (lane & 3) * 8;

  const unsigned short* Ab = A + (size_t)o0 * 512;
  const unsigned short* Bb = Bt + ((size_t)b*4096 + n0) * 512;

  bool vsw[4];
  #pragma unroll
  for (int fr = 0; fr < 4; fr++) {
    const int ob = o0 + wr*64 + fr*16;
    vsw[fr] = (MODE == 0) && ((ob % 192) >> 6) == 2;
  }

  floatx4 acc[4][4];
  #pragma unroll
  for (int i = 0; i < 4; i++)
    #pragma unroll
    for (int j = 0; j < 4; j++) acc[i][j] = (floatx4){0.f,0.f,0.f,0.f};

  for (int k0 = 0; k0 < 512; k0 += 32) {
    __syncthreads();
    #pragma unroll
    for (int cc = 0; cc < 2; cc++) {
      int ch = wave*2 + cc;
      async16(Ab + (size_t)(ch*16 + srow)*512 + k0 + scol, &As[ch*512]);
      async16(Bb + (size_t)(ch*16 + srow)*512 + k0 + scol, &Bs[ch*512]);
    }
    __syncthreads();
    short8 af[4], bf[4];
    #pragma unroll
    for (int f = 0; f < 4; f++) {
      af[f] = *(const short8*)&As[(wr*64 + f*16 + fm)*32 + fq*8];
      bf[f] = *(const short8*)&Bs[(wc*64 + f*16 + fm)*32 + fq*8];
    }
    #pragma unroll
    for (int fr = 0; fr < 4; fr++) {
      if (vsw[fr]) {
        #pragma unroll
        for (int fc = 0; fc < 4; fc++)
          acc[fr][fc] = __builtin_amdgcn_mfma_f32_16x16x32_bf16(bf[fc], af[fr], acc[fr][fc], 0, 0, 0);
      } else {
        #pragma unroll
        for (int fc = 0; fc < 4; fc++)
          acc[fr][fc] = __builtin_amdgcn_mfma_f32_16x16x32_bf16(af[fr], bf[fc], acc[fr][fc], 0, 0, 0);
      }
    }
  }

  if (MODE == 0) {
    #pragma unroll
    for (int fr = 0; fr < 4; fr++) {
      const int ob     = o0 + wr*64 + fr*16;
      const int head   = ob / 192;
      const int rem    = ob % 192;
      const int region = rem >> 6;             // 0=q 1=k 2=v
      const int bhh    = b*8 + head;
      #pragma unroll
      for (int fc = 0; fc < 4; fc++) {
        if (region == 0) {
          const int i = n0 + wc*64 + fc*16 + fm;
          const int dsub = (rem & 63) + fq*4;
          unsigned short t4[4];
          #pragma unroll
          for (int r = 0; r < 4; r++) t4[r] = f2bf(acc[fr][fc][r] * 0.18033688f);
          uint2 o; o.x = pack2(t4[0], t4[1]); o.y = pack2(t4[2], t4[3]);
          *(uint2*)&q_t[((size_t)bhh*4096 + i)*64 + dsub] = o;
        } else if (region == 1) {
          const int i = n0 + wc*64 + fc*16 + fm;
          const int dsub = (rem & 63) + fq*4;
          unsigned short t4[4];
          #pragma unroll
          for (int r = 0; r < 4; r++) t4[r] = f2bf(acc[fr][fc][r]);
          uint2 o; o.x = pack2(t4[0], t4[1]); o.y = pack2(t4[2], t4[3]);
          *(uint2*)&k_t[((size_t)bhh*4096 + i)*64 + dsub] = o;
        } else {
          // swapped orientation: rows = tokens, col o = ob + fm
          const int dsub = (rem & 63) + fm;
          const int tok0 = n0 + wc*64 + fc*16 + fq*4;
          unsigned short t4[4];
          #pragma unroll
          for (int r = 0; r < 4; r++) t4[r] = f2bf(acc[fr][fc][r]);
          uint2 o; o.x = pack2(t4[0], t4[1]); o.y = pack2(t4[2], t4[3]);
          *(uint2*)&v_[((size_t)bhh*64 + dsub)*4096 + tok0] = o;
        }
      }
    }
  } else {
    #pragma unroll
    for (int fr = 0; fr < 4; fr++)
      #pragma unroll
      for (int fc = 0; fc < 4; fc++) {
        const int i = n0 + wc*64 + fc*16 + fm;
        #pragma unroll
        for (int r = 0; r < 4; r++) {
          const int o = o0 + wr*64 + fr*16 + fq*4 + r;
          const size_t idx = ((size_t)b*512 + o)*4096 + i;
          outp[idx] = xres[idx] + pbias[o] + acc[fr][fc][r];
        }
      }
  }
}

// ---------------------------------------------------------------- attention
// q_t,k_t: [16][4096][64] bf16 (q pre-scaled by 0.125*log2e); v: [16][64][4096]
// 32x32 scheme: S^T via mfma_32x32x16 (A=K rows j, B=Q cols i=lane&31).
// P stays in REGISTERS: C-layout reg group 4t..4t+3 == A-frag of mfma_32x32x8
// for j-subtile t (j_local = 8t + 4*(lane>>5) + 0..3). No P LDS round-trip.
__global__ __launch_bounds__(256, 2)
void attn_kernel(const unsigned short* __restrict__ q_t,
                 const unsigned short* __restrict__ k_t,
                 const unsigned short* __restrict__ v_,
                 unsigned short* __restrict__ hout_t) {
  __shared__ __align__(16) unsigned short Ks[2][64*72];   // [j][k], +pad
  __shared__ __align__(16) unsigned short Vs[2][64*72];   // [d][j], +pad

  const int bh  = blockIdx.x;       // x = bh -> K/V L2 locality per XCD
  const int q0  = blockIdx.y * 128;
  const int tid = threadIdx.x;
  const int wave = tid >> 6, lane = tid & 63;
  const int ln = lane & 31, h = lane >> 5;

  // Q B-frags (32x32x16): B[k=kc*16+h*8+t][n=ln], i = q0+wave*32+ln
  short8 qf[4];
  {
    const unsigned short* qrow = q_t + ((size_t)bh*4096 + q0 + wave*32 + ln)*64;
    #pragma unroll
    for (int kc = 0; kc < 4; kc++)
      qf[kc] = *(const short8*)(qrow + kc*16 + h*8);
  }

  floatx16 o_acc[2];
  #pragma unroll
  for (int dn = 0; dn < 2; dn++)
    #pragma unroll
    for (int r = 0; r < 16; r++) o_acc[dn][r] = 0.f;
  float l = 0.f;  // per-lane partial denominator for col i = q0+wave*32+ln

  const int sr = tid >> 3;          // 0..31
  const int sc = (tid & 7) * 8;
  const unsigned short* kbase = k_t + (size_t)bh*262144;
  const unsigned short* vbase = v_  + (size_t)bh*262144;

  // preload tile 0 into registers
  uint4 kr0 = *(const uint4*)&kbase[(size_t)sr*64 + sc];
  uint4 kr1 = *(const uint4*)&kbase[(size_t)(sr+32)*64 + sc];
  uint4 vr0 = *(const uint4*)&vbase[(size_t)sr*4096 + sc];
  uint4 vr1 = *(const uint4*)&vbase[(size_t)(sr+32)*4096 + sc];

  for (int it = 0; it < 64; it++) {
    unsigned short* Kc = Ks[it & 1];
    unsigned short* Vc = Vs[it & 1];
    *(uint4*)&Kc[sr*72 + sc]      = kr0;
    *(uint4*)&Kc[(sr+32)*72 + sc] = kr1;
    *(uint4*)&Vc[sr*72 + sc]      = vr0;
    *(uint4*)&Vc[(sr+32)*72 + sc] = vr1;
    __syncthreads();

    // issue next tile's global loads (latency hidden behind compute)
    {
      const int jn = ((it + 1) & 63) * 64;
      kr0 = *(const uint4*)&kbase[(size_t)(jn + sr)*64 + sc];
      kr1 = *(const uint4*)&kbase[(size_t)(jn + sr + 32)*64 + sc];
      vr0 = *(const uint4*)&vbase[(size_t)sr*4096 + jn + sc];
      vr1 = *(const uint4*)&vbase[(size_t)(sr+32)*4096 + jn + sc];
    }

    // S^T = K Q^T : two 32x32 tiles (mj), K=64 over 4 chunks
    floatx16 st[2];
    #pragma unroll
    for (int mj = 0; mj < 2; mj++) {
      #pragma unroll
      for (int r = 0; r < 16; r++) st[mj][r] = 0.f;
      #pragma unroll
      for (int kc = 0; kc < 4; kc++) {
        short8 kA = *(const short8*)&Kc[(mj*32 + ln)*72 + kc*16 + h*8];
        st[mj] = __builtin_amdgcn_mfma_f32_32x32x16_bf16(kA, qf[kc], st[mj], 0, 0, 0);
      }
    }

    // p = exp2(s'), accumulate l, pack pairs of regs -> bf16 dwords
    unsigned pk[2][8];
    #pragma unroll
    for (int mj = 0; mj < 2; mj++) {
      #pragma unroll
      for (int rp = 0; rp < 8; rp++) {
        float p0 = fast_exp2(st[mj][2*rp]);
        float p1 = fast_exp2(st[mj][2*rp + 1]);
        l += p0 + p1;
        pk[mj][rp] = __builtin_amdgcn_perm(rbits(p1), rbits(p0), 0x07060302u);
      }
    }

    // O += P V via 32x32x8: A-frag for subtile t = regs 4t..4t+3 (pk[2t],pk[2t+1])
    #pragma unroll
    for (int mj = 0; mj < 2; mj++) {
      #pragma unroll
      for (int t = 0; t < 4; t++) {
        union { unsigned u[2]; short4v s; } uu;
        uu.u[0] = pk[mj][2*t]; uu.u[1] = pk[mj][2*t + 1];
        const short4v af = uu.s;
        #pragma unroll
        for (int dn = 0; dn < 2; dn++) {
          const short4v vf = *(const short4v*)&Vc[(dn*32 + ln)*72 + mj*32 + t*8 + h*4];
          o_acc[dn] = __builtin_amdgcn_mfma_f32_32x32x8bf16_1k(af, vf, o_acc[dn], 0, 0, 0);
        }
      }
    }
  }

  // finalize: full column sums, then divide + store
  l += __shfl_xor(l, 32, 64);
  const float linv = 1.f / l;   // lane ln holds 1/l for row i = q0+wave*32+ln

  const int bb = bh >> 3;
  const int cb = (bh & 7) * 64;
  #pragma unroll
  for (int r = 0; r < 16; r++) {
    const int il = (r & 3) + 8*(r >> 2) + 4*h;
    const float inv = __shfl(linv, il, 64);
    const int i = q0 + wave*32 + il;
    unsigned short* dst = &hout_t[((size_t)bb*4096 + i)*512 + cb + ln];
    dst[0]  = f2bf(o_acc[0][r] * inv);
    dst[32] = f2bf(o_acc[1][r] * inv);
  }
}

// ---------------------------------------------------------------- launcher
extern "C" void kernel_launch(void* const* d_in, const int* in_sizes, int n_in,
                              void* d_out, int out_size, void* d_ws, size_t ws_size,
                              hipStream_t stream) {
  (void)in_sizes; (void)n_in; (void)out_size; (void)ws_size;
  const float* x      = (const float*)d_in[0];
  const float* qkv_w  = (const float*)d_in[1];
  const float* proj_w = (const float*)d_in[2];
  const float* proj_b = (const float*)d_in[3];
  const float* gn_w   = (const float*)d_in[4];
  const float* gn_b   = (const float*)d_in[5];
  float* out = (float*)d_out;

  char* ws = (char*)d_ws;
  unsigned short* h_t   = (unsigned short*)(ws);                      // 8 MB, reused as hout_t
  unsigned short* q_t   = (unsigned short*)(ws + ((size_t)8  << 20));
  unsigned short* k_t   = (unsigned short*)(ws + ((size_t)16 << 20));
  unsigned short* v_    = (unsigned short*)(ws + ((size_t)24 << 20));
  unsigned short* wqkv  = (unsigned short*)(ws + ((size_t)32 << 20));
  unsigned short* wproj = (unsigned short*)(ws + ((size_t)34 << 20));
  float* stats          = (float*)(ws + ((size_t)35 << 20));
  unsigned short* hout_t = h_t;

  gn_stats<<<dim3(64), dim3(256), 0, stream>>>(x, stats);
  gn_apply_t<<<dim3(64, 8, 2), dim3(256), 0, stream>>>(x, stats, gn_w, gn_b, h_t);
  castw2<<<dim3(1024), dim3(256), 0, stream>>>(qkv_w, wqkv, 196608, proj_w, wproj);
  gemm_bt<0><<<dim3(32, 12, 2), dim3(256), 0, stream>>>(wqkv, h_t, q_t, k_t, v_,
                                                        nullptr, nullptr, nullptr);
  attn_kernel<<<dim3(16, 32), dim3(256), 0, stream>>>(q_t, k_t, v_, hout_t);
  gemm_bt<1><<<dim3(32, 4, 2), dim3(256), 0, stream>>>(wproj, hout_t,
                                                       nullptr, nullptr, nullptr,
                                                       out, x, proj_b);
}

// Round 5
// 232.897 us; speedup vs baseline: 1.0022x; 1.0022x over previous
//
#include <hip/hip_runtime.h>
#include <math.h>

typedef __attribute__((ext_vector_type(8))) short short8;
typedef __attribute__((ext_vector_type(4))) short short4v;
typedef __attribute__((ext_vector_type(4))) float floatx4;
typedef __attribute__((ext_vector_type(16))) float floatx16;

__device__ __forceinline__ unsigned short f2bf(float f) {
  union { float f; unsigned int u; } v; v.f = f;
  unsigned int r = v.u + 0x7fffu + ((v.u >> 16) & 1u);
  return (unsigned short)(r >> 16);
}

__device__ __forceinline__ float bf2f(unsigned short h) {
  union { unsigned int u; float f; } v; v.u = ((unsigned int)h) << 16;
  return v.f;
}

__device__ __forceinline__ unsigned int pack2(unsigned short a, unsigned short b) {
  return (unsigned int)a | ((unsigned int)b << 16);
}

__device__ __forceinline__ unsigned int rbits(float f) {
  union { float f; unsigned int u; } v; v.f = f;
  return v.u + 0x8000u;  // round-half-up to bf16 when >>16
}

__device__ __forceinline__ float fast_exp2(float x) {
#if __has_builtin(__builtin_amdgcn_exp2f)
  return __builtin_amdgcn_exp2f(x);
#else
  return exp2f(x);
#endif
}

// async global->LDS, 16B per lane. LDS dest is wave-uniform base + lane*16.
__device__ __forceinline__ void async16(const unsigned short* gp, unsigned short* lp) {
  __builtin_amdgcn_global_load_lds(
      (__attribute__((address_space(1))) void*)(gp),
      (__attribute__((address_space(3))) void*)(lp), 16, 0, 0);
}

// ---------------------------------------------------------------- GroupNorm
__global__ void gn_stats(const float* __restrict__ x, float* __restrict__ stats) {
  int bg = blockIdx.x;
  const float4* p = (const float4*)(x + (size_t)bg * 65536);
  float s = 0.f, ss = 0.f;
  for (int i = threadIdx.x; i < 16384; i += 256) {
    float4 v = p[i];
    s  += v.x + v.y + v.z + v.w;
    ss += v.x*v.x + v.y*v.y + v.z*v.z + v.w*v.w;
  }
  #pragma unroll
  for (int off = 32; off >= 1; off >>= 1) {
    s  += __shfl_xor(s,  off, 64);
    ss += __shfl_xor(ss, off, 64);
  }
  __shared__ float red[2][4];
  int wv = threadIdx.x >> 6;
  if ((threadIdx.x & 63) == 0) { red[0][wv] = s; red[1][wv] = ss; }
  __syncthreads();
  if (threadIdx.x == 0) {
    s  = red[0][0] + red[0][1] + red[0][2] + red[0][3];
    ss = red[1][0] + red[1][1] + red[1][2] + red[1][3];
    float mean = s * (1.f/65536.f);
    float var  = ss * (1.f/65536.f) - mean*mean;
    stats[2*bg]   = mean;
    stats[2*bg+1] = rsqrtf(var + 1e-5f);
  }
}

// normalize + cast bf16 + transpose to token-major h_t[B][HW][C]
__global__ void gn_apply_t(const float* __restrict__ x, const float* __restrict__ stats,
                           const float* __restrict__ gw, const float* __restrict__ gb,
                           unsigned short* __restrict__ h_t) {
  __shared__ __align__(16) unsigned short tile[64][72];
  const int b = blockIdx.z, c0 = blockIdx.y * 64, hw0 = blockIdx.x * 64;
  const int t = threadIdx.x;
  {
    const int cl = t >> 2;
    const int hs = (t & 3) * 16;
    const int c  = c0 + cl;
    const int g  = c >> 4;
    const float mean = stats[2*(b*32 + g)];
    const float rstd = stats[2*(b*32 + g) + 1];
    const float w  = gw[c] * rstd;
    const float bb = gb[c] - mean * w;
    const float4* src = (const float4*)(x + ((size_t)(b*512 + c))*4096 + hw0 + hs);
    #pragma unroll
    for (int i = 0; i < 4; i++) {
      float4 vv = src[i];
      unsigned short* d = &tile[cl][hs + i*4];
      d[0] = f2bf(vv.x*w + bb); d[1] = f2bf(vv.y*w + bb);
      d[2] = f2bf(vv.z*w + bb); d[3] = f2bf(vv.w*w + bb);
    }
  }
  __syncthreads();
  {
    const int hwl = t >> 2;
    const int cs  = (t & 3) * 16;
    uint4 w0, w1;
    w0.x = pack2(tile[cs+ 0][hwl], tile[cs+ 1][hwl]);
    w0.y = pack2(tile[cs+ 2][hwl], tile[cs+ 3][hwl]);
    w0.z = pack2(tile[cs+ 4][hwl], tile[cs+ 5][hwl]);
    w0.w = pack2(tile[cs+ 6][hwl], tile[cs+ 7][hwl]);
    w1.x = pack2(tile[cs+ 8][hwl], tile[cs+ 9][hwl]);
    w1.y = pack2(tile[cs+10][hwl], tile[cs+11][hwl]);
    w1.z = pack2(tile[cs+12][hwl], tile[cs+13][hwl]);
    w1.w = pack2(tile[cs+14][hwl], tile[cs+15][hwl]);
    unsigned short* dst = h_t + ((size_t)(b*4096 + hw0 + hwl))*512 + c0 + cs;
    *(uint4*)dst       = w0;
    *(uint4*)(dst + 8) = w1;
  }
}

// fp32 -> bf16 cast, two arrays in one launch
__global__ void castw2(const float* __restrict__ sa, unsigned short* __restrict__ da, int n4a,
                       const float* __restrict__ sb, unsigned short* __restrict__ db) {
  int i = blockIdx.x * 256 + threadIdx.x;
  const float* s; unsigned short* d;
  if (i < n4a) { s = sa; d = da; }
  else { i -= n4a; s = sb; d = db; }
  float4 vv = ((const float4*)s)[i];
  uint2 o;
  o.x = pack2(f2bf(vv.x), f2bf(vv.y));
  o.y = pack2(f2bf(vv.z), f2bf(vv.w));
  ((uint2*)d)[i] = o;
}

// ---------------------------------------------------------------- GEMM (bt)
// OUT[o][n] = sum_k A[o][k] * Bt[n][k]
// MODE 0: qkv epilogue -> q_t/k_t/v scatter; q pre-scaled by 0.125*log2(e).
//         v-region fragments use SWAPPED mfma operands -> coalesced b64 stores.
// MODE 1: proj epilogue -> out = x + bias + acc  (fp32)
template <int MODE>
__global__ __launch_bounds__(256, 2)
void gemm_bt(const unsigned short* __restrict__ A,
             const unsigned short* __restrict__ Bt,
             unsigned short* __restrict__ q_t,
             unsigned short* __restrict__ k_t,
             unsigned short* __restrict__ v_,
             float* __restrict__ outp,
             const float* __restrict__ xres,
             const float* __restrict__ pbias) {
  __shared__ __align__(16) unsigned short As[128*32];
  __shared__ __align__(16) unsigned short Bs[128*32];
  const int b   = blockIdx.z;
  const int n0  = blockIdx.x * 128;
  const int o0  = blockIdx.y * 128;
  const int tid = threadIdx.x;
  const int wave = tid >> 6, lane = tid & 63;
  const int wr = wave >> 1, wc = wave & 1;
  const int fm = lane & 15, fq = lane >> 4;
  const int srow = lane >> 2, scol = (lane & 3) * 8;

  const unsigned short* Ab = A + (size_t)o0 * 512;
  const unsigned short* Bb = Bt + ((size_t)b*4096 + n0) * 512;

  bool vsw[4];
  #pragma unroll
  for (int fr = 0; fr < 4; fr++) {
    const int ob = o0 + wr*64 + fr*16;
    vsw[fr] = (MODE == 0) && ((ob % 192) >> 6) == 2;
  }

  floatx4 acc[4][4];
  #pragma unroll
  for (int i = 0; i < 4; i++)
    #pragma unroll
    for (int j = 0; j < 4; j++) acc[i][j] = (floatx4){0.f,0.f,0.f,0.f};

  for (int k0 = 0; k0 < 512; k0 += 32) {
    __syncthreads();
    #pragma unroll
    for (int cc = 0; cc < 2; cc++) {
      int ch = wave*2 + cc;
      async16(Ab + (size_t)(ch*16 + srow)*512 + k0 + scol, &As[ch*512]);
      async16(Bb + (size_t)(ch*16 + srow)*512 + k0 + scol, &Bs[ch*512]);
    }
    __syncthreads();
    short8 af[4], bf[4];
    #pragma unroll
    for (int f = 0; f < 4; f++) {
      af[f] = *(const short8*)&As[(wr*64 + f*16 + fm)*32 + fq*8];
      bf[f] = *(const short8*)&Bs[(wc*64 + f*16 + fm)*32 + fq*8];
    }
    #pragma unroll
    for (int fr = 0; fr < 4; fr++) {
      if (vsw[fr]) {
        #pragma unroll
        for (int fc = 0; fc < 4; fc++)
          acc[fr][fc] = __builtin_amdgcn_mfma_f32_16x16x32_bf16(bf[fc], af[fr], acc[fr][fc], 0, 0, 0);
      } else {
        #pragma unroll
        for (int fc = 0; fc < 4; fc++)
          acc[fr][fc] = __builtin_amdgcn_mfma_f32_16x16x32_bf16(af[fr], bf[fc], acc[fr][fc], 0, 0, 0);
      }
    }
  }

  if (MODE == 0) {
    #pragma unroll
    for (int fr = 0; fr < 4; fr++) {
      const int ob     = o0 + wr*64 + fr*16;
      const int head   = ob / 192;
      const int rem    = ob % 192;
      const int region = rem >> 6;             // 0=q 1=k 2=v
      const int bhh    = b*8 + head;
      #pragma unroll
      for (int fc = 0; fc < 4; fc++) {
        if (region == 0) {
          const int i = n0 + wc*64 + fc*16 + fm;
          const int dsub = (rem & 63) + fq*4;
          unsigned short t4[4];
          #pragma unroll
          for (int r = 0; r < 4; r++) t4[r] = f2bf(acc[fr][fc][r] * 0.18033688f);
          uint2 o; o.x = pack2(t4[0], t4[1]); o.y = pack2(t4[2], t4[3]);
          *(uint2*)&q_t[((size_t)bhh*4096 + i)*64 + dsub] = o;
        } else if (region == 1) {
          const int i = n0 + wc*64 + fc*16 + fm;
          const int dsub = (rem & 63) + fq*4;
          unsigned short t4[4];
          #pragma unroll
          for (int r = 0; r < 4; r++) t4[r] = f2bf(acc[fr][fc][r]);
          uint2 o; o.x = pack2(t4[0], t4[1]); o.y = pack2(t4[2], t4[3]);
          *(uint2*)&k_t[((size_t)bhh*4096 + i)*64 + dsub] = o;
        } else {
          const int dsub = (rem & 63) + fm;
          const int tok0 = n0 + wc*64 + fc*16 + fq*4;
          unsigned short t4[4];
          #pragma unroll
          for (int r = 0; r < 4; r++) t4[r] = f2bf(acc[fr][fc][r]);
          uint2 o; o.x = pack2(t4[0], t4[1]); o.y = pack2(t4[2], t4[3]);
          *(uint2*)&v_[((size_t)bhh*64 + dsub)*4096 + tok0] = o;
        }
      }
    }
  } else {
    #pragma unroll
    for (int fr = 0; fr < 4; fr++)
      #pragma unroll
      for (int fc = 0; fc < 4; fc++) {
        const int i = n0 + wc*64 + fc*16 + fm;
        #pragma unroll
        for (int r = 0; r < 4; r++) {
          const int o = o0 + wr*64 + fr*16 + fq*4 + r;
          const size_t idx = ((size_t)b*512 + o)*4096 + i;
          outp[idx] = xres[idx] + pbias[o] + acc[fr][fc][r];
        }
      }
  }
}

// ---------------------------------------------------------------- attention
// q_t,k_t: [16][4096][64] bf16 (q pre-scaled by 0.125*log2e); v: [16][64][4096]
// 32x32 scheme, P kept in registers (S^T C-layout == PV A-layout per 8-j subtile).
// V staged into LDS with j-interleave [0-3,8-11,16-19,24-27 | 4-7,...] per 32-j
// block so PV B-frags read as b128 (2 subtiles per read).
// SPLIT=1: j-range [js*2048,(js+1)*2048), bf16 O-partials + fp32 l-partials.
// SPLIT=0: full j-range, writes hout_t directly.
template <int SPLIT>
__global__ __launch_bounds__(256, 4)
void attn_kernel(const unsigned short* __restrict__ q_t,
                 const unsigned short* __restrict__ k_t,
                 const unsigned short* __restrict__ v_,
                 unsigned short* __restrict__ hout_t,
                 unsigned short* __restrict__ o_part,
                 float* __restrict__ l_part) {
  __shared__ __align__(16) unsigned short Ks[2][64*72];   // [j][k], +pad
  __shared__ __align__(16) unsigned short Vs[2][64*72];   // [d][j-interleaved], +pad

  const int bh  = blockIdx.x;
  const int q0  = blockIdx.y * 128;
  const int js  = SPLIT ? blockIdx.z : 0;
  const int nit = SPLIT ? 32 : 64;
  const int jbase = js * 2048;
  const int tid = threadIdx.x;
  const int wave = tid >> 6, lane = tid & 63;
  const int ln = lane & 31, h = lane >> 5;

  // Q B-frags (32x32x16): B[k=kc*16+h*8+t][n=ln], i = q0+wave*32+ln
  short8 qf[4];
  {
    const unsigned short* qrow = q_t + ((size_t)bh*4096 + q0 + wave*32 + ln)*64;
    #pragma unroll
    for (int kc = 0; kc < 4; kc++)
      qf[kc] = *(const short8*)(qrow + kc*16 + h*8);
  }

  const floatx16 z16 = {0.f,0.f,0.f,0.f,0.f,0.f,0.f,0.f,
                        0.f,0.f,0.f,0.f,0.f,0.f,0.f,0.f};
  floatx16 o_acc[2];
  o_acc[0] = z16; o_acc[1] = z16;
  float l = 0.f;

  const int sr = tid >> 3;          // 0..31
  const int sc = (tid & 7) * 8;     // source 8-short chunk
  const int c  = tid & 7;           // chunk id within 64-j row
  // V interleave destination: chunk c (j = c*8..c*8+7) -> lo 4 at pos, hi 4 at pos+16
  const int vpos = ((c >> 2) * 32) + ((c & 3) * 4);
  const unsigned short* kbase = k_t + (size_t)bh*262144;
  const unsigned short* vbase = v_  + (size_t)bh*262144;

  // preload tile 0 into registers
  uint4 kr0 = *(const uint4*)&kbase[(size_t)(jbase + sr)*64 + sc];
  uint4 kr1 = *(const uint4*)&kbase[(size_t)(jbase + sr + 32)*64 + sc];
  uint4 vr0 = *(const uint4*)&vbase[(size_t)sr*4096 + jbase + sc];
  uint4 vr1 = *(const uint4*)&vbase[(size_t)(sr+32)*4096 + jbase + sc];

  for (int it = 0; it < nit; it++) {
    unsigned short* Kc = Ks[it & 1];
    unsigned short* Vc = Vs[it & 1];
    *(uint4*)&Kc[sr*72 + sc]      = kr0;
    *(uint4*)&Kc[(sr+32)*72 + sc] = kr1;
    *(uint2*)&Vc[sr*72 + vpos]           = *(const uint2*)&vr0;
    *(uint2*)&Vc[sr*72 + vpos + 16]      = *((const uint2*)&vr0 + 1);
    *(uint2*)&Vc[(sr+32)*72 + vpos]      = *(const uint2*)&vr1;
    *(uint2*)&Vc[(sr+32)*72 + vpos + 16] = *((const uint2*)&vr1 + 1);
    __syncthreads();

    // issue next tile's global loads (latency hidden behind compute)
    {
      const int jn = jbase + (((it + 1) & (nit - 1)) * 64);
      kr0 = *(const uint4*)&kbase[(size_t)(jn + sr)*64 + sc];
      kr1 = *(const uint4*)&kbase[(size_t)(jn + sr + 32)*64 + sc];
      vr0 = *(const uint4*)&vbase[(size_t)sr*4096 + jn + sc];
      vr1 = *(const uint4*)&vbase[(size_t)(sr+32)*4096 + jn + sc];
    }

    // one 32-j subtile (mj) at a time: QK -> exp/pack -> PV (lower reg pressure)
    #pragma unroll
    for (int mj = 0; mj < 2; mj++) {
      // S^T = K Q^T
      floatx16 st;
      {
        short8 kA = *(const short8*)&Kc[(mj*32 + ln)*72 + h*8];
        st = __builtin_amdgcn_mfma_f32_32x32x16_bf16(kA, qf[0], z16, 0, 0, 0);
      }
      #pragma unroll
      for (int kc = 1; kc < 4; kc++) {
        short8 kA = *(const short8*)&Kc[(mj*32 + ln)*72 + kc*16 + h*8];
        st = __builtin_amdgcn_mfma_f32_32x32x16_bf16(kA, qf[kc], st, 0, 0, 0);
      }

      // p = exp2(s'), accumulate l, pack to bf16 pairs
      unsigned pk[8];
      #pragma unroll
      for (int rp = 0; rp < 8; rp++) {
        float p0 = fast_exp2(st[2*rp]);
        float p1 = fast_exp2(st[2*rp + 1]);
        l += p0 + p1;
        pk[rp] = __builtin_amdgcn_perm(rbits(p1), rbits(p0), 0x07060302u);
      }

      // O += P V via 32x32x8: subtile t A-frag = pk[2t],pk[2t+1];
      // V b128 covers subtiles 2*t2 and 2*t2+1 (interleaved layout)
      #pragma unroll
      for (int t2 = 0; t2 < 2; t2++) {
        union { unsigned u[2]; short4v s; } a0, a1;
        a0.u[0] = pk[4*t2];     a0.u[1] = pk[4*t2 + 1];
        a1.u[0] = pk[4*t2 + 2]; a1.u[1] = pk[4*t2 + 3];
        #pragma unroll
        for (int dn = 0; dn < 2; dn++) {
          short8 vv = *(const short8*)&Vc[(dn*32 + ln)*72 + mj*32 + h*16 + t2*8];
          short4v vlo = __builtin_shufflevector(vv, vv, 0, 1, 2, 3);
          short4v vhi = __builtin_shufflevector(vv, vv, 4, 5, 6, 7);
          o_acc[dn] = __builtin_amdgcn_mfma_f32_32x32x8bf16_1k(a0.s, vlo, o_acc[dn], 0, 0, 0);
          o_acc[dn] = __builtin_amdgcn_mfma_f32_32x32x8bf16_1k(a1.s, vhi, o_acc[dn], 0, 0, 0);
        }
      }
    }
  }

  // column sums complete within lane pairs (h=0/1)
  l += __shfl_xor(l, 32, 64);

  if (SPLIT) {
    unsigned short* op = o_part + (((size_t)(js*16 + bh)*4096 + q0 + wave*32) * 64);
    #pragma unroll
    for (int r = 0; r < 16; r++) {
      const int il = (r & 3) + 8*(r >> 2) + 4*h;
      op[(size_t)il*64 + ln]      = f2bf(o_acc[0][r]);
      op[(size_t)il*64 + 32 + ln] = f2bf(o_acc[1][r]);
    }
    if (lane < 32)
      l_part[(size_t)(js*16 + bh)*4096 + q0 + wave*32 + lane] = l;
  } else {
    const float linv = 1.f / l;
    const int bb = bh >> 3;
    const int cb = (bh & 7) * 64;
    #pragma unroll
    for (int r = 0; r < 16; r++) {
      const int il = (r & 3) + 8*(r >> 2) + 4*h;
      const float inv = __shfl(linv, il, 64);
      const int i = q0 + wave*32 + il;
      unsigned short* dst = &hout_t[((size_t)bb*4096 + i)*512 + cb + ln];
      dst[0]  = f2bf(o_acc[0][r] * inv);
      dst[32] = f2bf(o_acc[1][r] * inv);
    }
  }
}

// combine: hout = (O0+O1)/(l0+l1), bf16 token-major
__global__ void attn_combine(const unsigned short* __restrict__ o_part,
                             const float* __restrict__ l_part,
                             unsigned short* __restrict__ hout_t) {
  const int bh = blockIdx.x;
  const int i0 = blockIdx.y * 64;
  const int t  = threadIdx.x;
  const int d4 = (t & 15) * 4;
  const int il = t >> 4;
  const int bb = bh >> 3;
  const int cb = (bh & 7) * 64;
  const size_t JS = (size_t)16 * 4096 * 64;   // js stride in o_part
  #pragma unroll
  for (int p = 0; p < 4; p++) {
    const int i = i0 + p*16 + il;
    const size_t ob = ((size_t)bh*4096 + i)*64 + d4;
    uint2 a = *(const uint2*)&o_part[ob];
    uint2 b = *(const uint2*)&o_part[ob + JS];
    const size_t lb = (size_t)bh*4096 + i;
    const float inv = 1.f / (l_part[lb] + l_part[lb + 65536]);
    float o0 = (bf2f((unsigned short)(a.x & 0xffff)) + bf2f((unsigned short)(b.x & 0xffff))) * inv;
    float o1 = (bf2f((unsigned short)(a.x >> 16))    + bf2f((unsigned short)(b.x >> 16)))    * inv;
    float o2 = (bf2f((unsigned short)(a.y & 0xffff)) + bf2f((unsigned short)(b.y & 0xffff))) * inv;
    float o3 = (bf2f((unsigned short)(a.y >> 16))    + bf2f((unsigned short)(b.y >> 16)))    * inv;
    uint2 w;
    w.x = pack2(f2bf(o0), f2bf(o1));
    w.y = pack2(f2bf(o2), f2bf(o3));
    *(uint2*)&hout_t[((size_t)bb*4096 + i)*512 + cb + d4] = w;
  }
}

// ---------------------------------------------------------------- launcher
extern "C" void kernel_launch(void* const* d_in, const int* in_sizes, int n_in,
                              void* d_out, int out_size, void* d_ws, size_t ws_size,
                              hipStream_t stream) {
  (void)in_sizes; (void)n_in; (void)out_size;
  const float* x      = (const float*)d_in[0];
  const float* qkv_w  = (const float*)d_in[1];
  const float* proj_w = (const float*)d_in[2];
  const float* proj_b = (const float*)d_in[3];
  const float* gn_w   = (const float*)d_in[4];
  const float* gn_b   = (const float*)d_in[5];
  float* out = (float*)d_out;

  char* ws = (char*)d_ws;
  unsigned short* h_t   = (unsigned short*)(ws);                      // 8 MB, reused as hout_t
  unsigned short* q_t   = (unsigned short*)(ws + ((size_t)8  << 20));
  unsigned short* k_t   = (unsigned short*)(ws + ((size_t)16 << 20));
  unsigned short* v_    = (unsigned short*)(ws + ((size_t)24 << 20));
  unsigned short* wqkv  = (unsigned short*)(ws + ((size_t)32 << 20));
  unsigned short* wproj = (unsigned short*)(ws + ((size_t)34 << 20));
  float* stats          = (float*)(ws + ((size_t)35 << 20));
  unsigned short* o_part = (unsigned short*)(ws + ((size_t)36 << 20)); // 16 MB (bf16 x2 splits)
  float* l_part          = (float*)(ws + ((size_t)52 << 20));          // 512 KB
  unsigned short* hout_t = h_t;

  const bool split = ws_size >= (((size_t)52 << 20) + ((size_t)1 << 19));

  gn_stats<<<dim3(64), dim3(256), 0, stream>>>(x, stats);
  gn_apply_t<<<dim3(64, 8, 2), dim3(256), 0, stream>>>(x, stats, gn_w, gn_b, h_t);
  castw2<<<dim3(1024), dim3(256), 0, stream>>>(qkv_w, wqkv, 196608, proj_w, wproj);
  gemm_bt<0><<<dim3(32, 12, 2), dim3(256), 0, stream>>>(wqkv, h_t, q_t, k_t, v_,
                                                        nullptr, nullptr, nullptr);
  if (split) {
    attn_kernel<1><<<dim3(16, 32, 2), dim3(256), 0, stream>>>(q_t, k_t, v_, nullptr,
                                                              o_part, l_part);
    attn_combine<<<dim3(16, 64), dim3(256), 0, stream>>>(o_part, l_part, hout_t);
  } else {
    attn_kernel<0><<<dim3(16, 32), dim3(256), 0, stream>>>(q_t, k_t, v_, hout_t,
                                                           nullptr, nullptr);
  }
  gemm_bt<1><<<dim3(32, 4, 2), dim3(256), 0, stream>>>(wproj, hout_t,
                                                       nullptr, nullptr, nullptr,
                                                       out, x, proj_b);
}